// Round 7
// baseline (135.091 us; speedup 1.0000x reference)
//
#include <hip/hip_runtime.h>
#include <stdint.h>

// Problem constants (match reference)
constexpr int B = 4, C = 16, H = 512, W = 512;
constexpr int N = H * W;                   // pixels per batch plane (262144)
constexpr int PPT = 4;                     // pixels per thread
constexpr int BLOCK = 256;
constexpr int CHUNK = BLOCK * PPT;         // 1024 pixels per block
constexpr int BLK_PER_BATCH = N / CHUNK;   // 256
constexpr float EPS = 1e-10f;

// Three-phase scatter (racy store + block-deduped atomic fixup + resolve).
//   A: compute 4 px/thread; racy plain u64 store key=(n<<32)|zbits into
//      keys[b][t]; coalesced rec=(t<<32)|zbits per source.
//   B: block-wide LDS dedupe over the 1024-px window (exact-t hash compare:
//      skip only if a same-cell contender with larger n exists in-block).
//      Survivors read the cell (post-A state, monotone under atomicMax) and
//      atomicMax only if the observed winner could be smaller.
//   C: resolve winners vs original depth (4 px/thread).
// d_ws poison (0xAA) marks untouched cells: hi = 0xAAAAAAAA > N-1.

__global__ __launch_bounds__(256) void project_store_kernel(
    const float* __restrict__ depth,   // [B,1,H,W]
    const float* __restrict__ K,       // [B,3,3]
    const float* __restrict__ T,       // [B,C,4,4]
    const int*   __restrict__ masks,   // [B,C,H,W] (0/1)
    unsigned long long* __restrict__ keys, // [B,N] u64, poison-initialized
    unsigned long long* __restrict__ recs) // [B,N] u64 per-source (t<<32)|z
{
    __shared__ float Ts[16][17];       // Ts[e][c] = T[b][c][e]

    int b = blockIdx.x >> 8;                       // 256 blocks per batch
    int base = (blockIdx.x & (BLK_PER_BATCH - 1)) * CHUNK;
    int n0 = base + threadIdx.x * PPT;             // 4 consecutive pixels
    int idx0 = b * N + n0;
    int vrow = n0 >> 9;                            // same row for all 4
    int u0 = n0 & (W - 1);

    // stage T[b] (256 floats) into LDS, transposed
    {
        int t = threadIdx.x;           // t = c*16 + e
        int c = t >> 4, e = t & 15;
        Ts[e][c] = T[(size_t)b * 256 + t];
    }
    __syncthreads();

    float4 d4 = *(const float4*)(depth + idx0);
    float darr[PPT] = {d4.x, d4.y, d4.z, d4.w};

    // --- K[b] (block-uniform scalar loads) ---
    const float* Kb = K + b * 9;
    float k00 = Kb[0], k01 = Kb[1], k02 = Kb[2];
    float k10 = Kb[3], k11 = Kb[4], k12 = Kb[5];
    float k20 = Kb[6], k21 = Kb[7], k22 = Kb[8];

    // adjugate inverse
    float c00 =  (k11 * k22 - k12 * k21);
    float c01 = -(k10 * k22 - k12 * k20);
    float c02 =  (k10 * k21 - k11 * k20);
    float det = k00 * c00 + k01 * c01 + k02 * c02;
    float invdet = 1.0f / det;
    float i00 =  (k11 * k22 - k12 * k21) * invdet;
    float i01 = -(k01 * k22 - k02 * k21) * invdet;
    float i02 =  (k01 * k12 - k02 * k11) * invdet;
    float i10 = -(k10 * k22 - k12 * k20) * invdet;
    float i11 =  (k00 * k22 - k02 * k20) * invdet;
    float i12 = -(k00 * k12 - k02 * k10) * invdet;
    float i20 =  (k10 * k21 - k11 * k20) * invdet;
    float i21 = -(k00 * k21 - k01 * k20) * invdet;
    float i22 =  (k00 * k11 - k01 * k10) * invdet;

    float vf = (float)vrow;
    float rx = i01 * vf + i02;         // row-constant parts
    float ry = i11 * vf + i12;
    float rz = i21 * vf + i22;

    // --- mask sel for 4 pixels, 4-channel tiers from the top ---
    const int* mb = masks + (size_t)b * C * N + n0;
    int sel[PPT] = {-1, -1, -1, -1};
    {
        int4 m3 = *(const int4*)(mb + (size_t)15 * N);
        int4 m2 = *(const int4*)(mb + (size_t)14 * N);
        int4 m1 = *(const int4*)(mb + (size_t)13 * N);
        int4 m0 = *(const int4*)(mb + (size_t)12 * N);
        int a3[4] = {m3.x, m3.y, m3.z, m3.w};
        int a2[4] = {m2.x, m2.y, m2.z, m2.w};
        int a1[4] = {m1.x, m1.y, m1.z, m1.w};
        int a0[4] = {m0.x, m0.y, m0.z, m0.w};
        #pragma unroll
        for (int j = 0; j < PPT; ++j)
            sel[j] = a3[j] ? 15 : a2[j] ? 14 : a1[j] ? 13 : a0[j] ? 12 : -1;
        #pragma unroll
        for (int tier = 2; tier >= 0; --tier) {
            if (sel[0] < 0 || sel[1] < 0 || sel[2] < 0 || sel[3] < 0) {
                int cbase = tier * 4;
                int4 q3 = *(const int4*)(mb + (size_t)(cbase + 3) * N);
                int4 q2 = *(const int4*)(mb + (size_t)(cbase + 2) * N);
                int4 q1 = *(const int4*)(mb + (size_t)(cbase + 1) * N);
                int4 q0 = *(const int4*)(mb + (size_t)(cbase + 0) * N);
                int b3[4] = {q3.x, q3.y, q3.z, q3.w};
                int b2[4] = {q2.x, q2.y, q2.z, q2.w};
                int b1[4] = {q1.x, q1.y, q1.z, q1.w};
                int b0[4] = {q0.x, q0.y, q0.z, q0.w};
                #pragma unroll
                for (int j = 0; j < PPT; ++j)
                    if (sel[j] < 0)
                        sel[j] = b3[j] ? cbase + 3 : b2[j] ? cbase + 2
                               : b1[j] ? cbase + 1 : b0[j] ? cbase : -1;
            }
        }
    }

    unsigned long long rec[PPT];
    #pragma unroll
    for (int j = 0; j < PPT; ++j) {
        float d = darr[j];
        float uf = (float)(u0 + j);
        float px = (i00 * uf + rx) * d;
        float py = (i10 * uf + ry) * d;
        float pz = (i20 * uf + rz) * d;

        float ox = px, oy = py, oz = pz;
        int s = sel[j];
        if (s >= 0) {
            float tx = Ts[0][s]  * px + Ts[1][s]  * py + Ts[2][s]  * pz + Ts[3][s];
            float ty = Ts[4][s]  * px + Ts[5][s]  * py + Ts[6][s]  * pz + Ts[7][s];
            float tz = Ts[8][s]  * px + Ts[9][s]  * py + Ts[10][s] * pz + Ts[11][s];
            float tw = Ts[12][s] * px + Ts[13][s] * py + Ts[14][s] * pz + Ts[15][s];
            float denom = tw + EPS;
            ox = tx / denom;
            oy = ty / denom;
            oz = tz / denom;
        }

        float qx = k00 * ox + k01 * oy + k02 * oz;
        float qy = k10 * ox + k11 * oy + k12 * oz;
        float qz = k20 * ox + k21 * oy + k22 * oz;
        float zz = qz + EPS;
        float pu = qx / zz;
        float pv = qy / zz;
        pu = fminf(fmaxf(pu, 0.0f), (float)(W - 1));
        pv = fminf(fmaxf(pv, 0.0f), (float)(H - 1));
        int ui = (int)pu;
        int vi = (int)pv;
        unsigned t = (unsigned)(vi * W + ui);
        unsigned zbits = __float_as_uint(oz);

        rec[j] = ((unsigned long long)t << 32) | (unsigned long long)zbits;
        // racy plain 8B store — no atomic port
        keys[(size_t)b * N + t] =
            ((unsigned long long)(unsigned)(n0 + j) << 32)
            | (unsigned long long)zbits;
    }

    ulonglong2* rp = (ulonglong2*)(recs + idx0);
    rp[0] = make_ulonglong2(rec[0], rec[1]);
    rp[1] = make_ulonglong2(rec[2], rec[3]);
}

// Phase B: block-wide LDS dedupe, then atomic only where needed.
__global__ __launch_bounds__(256) void fixup_kernel(
    unsigned long long* __restrict__ keys,
    const unsigned long long* __restrict__ recs)
{
    __shared__ unsigned slot[CHUNK];   // hash: t & 1023 -> (t<<10)|local_n

    int b = blockIdx.x >> 8;
    int base = (blockIdx.x & (BLK_PER_BATCH - 1)) * CHUNK;
    int l0 = threadIdx.x * PPT;
    int idx0 = b * N + base + l0;

    #pragma unroll
    for (int j = 0; j < PPT; ++j) slot[threadIdx.x + j * BLOCK] = 0;
    __syncthreads();

    const ulonglong2* rp = (const ulonglong2*)(recs + idx0);
    ulonglong2 r01 = rp[0];
    ulonglong2 r23 = rp[1];
    unsigned long long rec[PPT] = {r01.x, r01.y, r23.x, r23.y};
    unsigned t[PPT], z[PPT];
    #pragma unroll
    for (int j = 0; j < PPT; ++j) {
        t[j] = (unsigned)(rec[j] >> 32);
        z[j] = (unsigned)rec[j];
        atomicMax(&slot[t[j] & (CHUNK - 1)],
                  (t[j] << 10) | (unsigned)(l0 + j));
    }
    __syncthreads();

    #pragma unroll
    for (int j = 0; j < PPT; ++j) {
        unsigned l = (unsigned)(l0 + j);
        unsigned v = slot[t[j] & (CHUNK - 1)];
        // dominated iff an exact same-t entry with strictly larger local n won
        if ((v >> 10) == t[j] && (v & (CHUNK - 1)) > l) continue;
        unsigned n = (unsigned)base + l;
        unsigned long long* cell = &keys[(size_t)b * N + t[j]];
        unsigned hi = (unsigned)(*cell >> 32);
        // Observed value is some contender's key (all phase-A stores are
        // visible). hi >= n => final >= key(n) already guaranteed.
        if (hi > (unsigned)(N - 1) || hi < n) {
            unsigned long long key =
                ((unsigned long long)n << 32) | (unsigned long long)z[j];
            atomicMax(cell, key);
        }
    }
}

// Phase C: resolve — winner's Z where touched, else original depth.
__global__ __launch_bounds__(256) void resolve_kernel(
    const unsigned long long* __restrict__ keys,
    const float*              __restrict__ depth,
    float*                    __restrict__ out)
{
    int idx0 = (blockIdx.x * BLOCK + threadIdx.x) * PPT;
    const ulonglong2* kp = (const ulonglong2*)(keys + idx0);
    ulonglong2 k01 = kp[0];
    ulonglong2 k23 = kp[1];
    unsigned long long k[PPT] = {k01.x, k01.y, k23.x, k23.y};
    float4 d4 = *(const float4*)(depth + idx0);
    float darr[PPT] = {d4.x, d4.y, d4.z, d4.w};
    float o[PPT];
    #pragma unroll
    for (int j = 0; j < PPT; ++j) {
        unsigned hi = (unsigned)(k[j] >> 32);
        o[j] = (hi <= (unsigned)(N - 1)) ? __uint_as_float((unsigned)k[j])
                                         : darr[j];
    }
    *(float4*)(out + idx0) = make_float4(o[0], o[1], o[2], o[3]);
}

extern "C" void kernel_launch(void* const* d_in, const int* in_sizes, int n_in,
                              void* d_out, int out_size, void* d_ws, size_t ws_size,
                              hipStream_t stream) {
    const float* depth = (const float*)d_in[0];   // [B,1,H,W] fp32
    const float* K     = (const float*)d_in[1];   // [B,3,3]   fp32
    const float* T     = (const float*)d_in[2];   // [B,C,4,4] fp32
    const int*   masks = (const int*)d_in[3];     // [B,C,H,W] int32 0/1
    float* out = (float*)d_out;                    // [B,1,H,W] fp32

    char* ws = (char*)d_ws;
    unsigned long long* keys = (unsigned long long*)ws;                 // 8 MB
    unsigned long long* recs = (unsigned long long*)(ws + (size_t)B * N * 8); // 8 MB

    int grid = B * BLK_PER_BATCH;      // 1024 blocks of 256 (4 px/thread)
    project_store_kernel<<<grid, BLOCK, 0, stream>>>(depth, K, T, masks, keys, recs);
    fixup_kernel<<<grid, BLOCK, 0, stream>>>(keys, recs);
    resolve_kernel<<<grid, BLOCK, 0, stream>>>(keys, depth, out);
}